// Round 8
// baseline (2536.638 us; speedup 1.0000x reference)
//
#include <hip/hip_runtime.h>
#include <hip/hip_cooperative_groups.h>
#include <math.h>

// HybridDecoder. B=1024 H=1024 IN=512 OUT=8192 T=15.
// R8: whole GRU chain = ONE cooperative launch (grid.sync between phases);
//     gemm256 gets L2-aware 2x4 supertile mapping under the XCD swizzle.
// conv_transpose identity: y[n,o,t] = sum_{2l+k=t} x[n,i,l] * W[o,i,k]

#define HD    1024
#define BATCH 1024
#define IND   512
#define OUTD  8192
#define TSTEPS 15
#define EPSV  1e-5f

typedef unsigned short u16;
typedef __attribute__((ext_vector_type(8))) short bf16x8;
typedef __attribute__((ext_vector_type(8))) unsigned short u16x8;
typedef __attribute__((ext_vector_type(4))) unsigned short u16x4;
typedef __attribute__((ext_vector_type(4))) float f32x4;

__device__ __forceinline__ u16 f2b(float f) {          // fp32 -> bf16 RNE
    union { float f; unsigned u; } x; x.f = f;
    unsigned r = x.u + 0x7fffu + ((x.u >> 16) & 1u);
    return (u16)(r >> 16);
}
__device__ __forceinline__ float b2f(u16 v) {
    union { unsigned u; float f; } x; x.u = ((unsigned)v) << 16; return x.f;
}

typedef __attribute__((address_space(1))) const void gas_t;
typedef __attribute__((address_space(3))) void las_t;
__device__ __forceinline__ void gload_lds16(const u16* g, u16* l) {
    __builtin_amdgcn_global_load_lds((gas_t*)g, (las_t*)l, 16, 0, 0);
}

// ===========================================================================
// 256x256 GEMM (bf16 in, fp32 or bf16 out): C = A@B^T + bias.
// 512 thr = 8 waves (2M x 4N); BK=64 double-buffered (128 KiB LDS).
// stage(kt+1) at tile top -> full-tile cover -> single {vmcnt(0); barrier}/tile.
// XCD swizzle + 2x4 supertile mapping (A 1MB + B 2MB = 3MB fits 4MB L2/XCD).
// ===========================================================================
template<int OUTB>
__launch_bounds__(512, 2)
__global__ void gemm256(int nbn, int nk,
    const u16* __restrict__ A, const u16* __restrict__ B,
    const float* __restrict__ bias, float* __restrict__ Cf,
    u16* __restrict__ Cb, int lda, int ldb, int ldc)
{
    // bijective XCD swizzle (m204)
    const int nwg = gridDim.x;
    const int q = nwg >> 3, r = nwg & 7;
    const int xcd = blockIdx.x & 7, idx = blockIdx.x >> 3;
    const int wg = (xcd < r ? xcd * (q + 1) : r * (q + 1) + (xcd - r) * q) + idx;
    // 2x4 supertile mapping for L2 reuse
    int bm, bn;
    const int nbm = nwg / nbn;
    if ((nbn & 3) == 0 && (nbm & 1) == 0) {
        const int nsc = nbn >> 2;
        const int super = wg >> 3, inner = wg & 7;
        const int sr = super / nsc, sc = super - sr * nsc;
        bm = (sr * 2 + (inner >> 2)) * 256;
        bn = (sc * 4 + (inner & 3)) * 256;
    } else {
        bm = (wg / nbn) * 256;
        bn = (wg % nbn) * 256;
    }

    __shared__ __align__(16) u16 smem[2][2][256 * 64];   // [A/B][buf][.]
    u16 (*As)[256 * 64] = smem[0];
    u16 (*Bs)[256 * 64] = smem[1];

    const int tid = threadIdx.x;
    const int w = tid >> 6, l = tid & 63;
    const int wr = w >> 2, wc = w & 3;       // 2M x 4N wave grid
    const int srow = l >> 3;                 // staging row in 8-row chunk
    const int scb  = (l & 7) ^ srow;         // swizzled SOURCE col-block
    const int fr = l & 15, fcb = l >> 4, swz = l & 7;

    const u16* Ag = A + (size_t)bm * lda;
    const u16* Bg = B + (size_t)bn * ldb;

    auto stage = [&](int b, int kt) {        // 8 gload_lds / thread
        const int k0 = kt * 64 + scb * 8;
#pragma unroll
        for (int rr = 0; rr < 4; ++rr)
            gload_lds16(Ag + (size_t)(rr * 64 + w * 8 + srow) * lda + k0,
                        &As[b][(rr * 64 + w * 8) * 64]);
#pragma unroll
        for (int rr = 0; rr < 4; ++rr)
            gload_lds16(Bg + (size_t)(rr * 64 + w * 8 + srow) * ldb + k0,
                        &Bs[b][(rr * 64 + w * 8) * 64]);
    };

    f32x4 acc[8][4];
#pragma unroll
    for (int m = 0; m < 8; ++m)
#pragma unroll
        for (int n = 0; n < 4; ++n) acc[m][n] = (f32x4){0.f, 0.f, 0.f, 0.f};

    stage(0, 0);
    asm volatile("s_waitcnt vmcnt(0)" ::: "memory");
    asm volatile("s_barrier" ::: "memory");

    for (int kt = 0; kt < nk; ++kt) {
        const int c = kt & 1;
        if (kt + 1 < nk) stage(c ^ 1, kt + 1);    // full-tile cover before wait
#pragma unroll
        for (int ks = 0; ks < 2; ++ks) {
            bf16x8 av[8], bv[4];
#pragma unroll
            for (int m = 0; m < 8; ++m)
                av[m] = *(const bf16x8*)&As[c][
                    (wr * 128 + m * 16 + fr) * 64 + (((ks * 4 + fcb) ^ swz) * 8)];
#pragma unroll
            for (int n = 0; n < 4; ++n)
                bv[n] = *(const bf16x8*)&Bs[c][
                    (wc * 64 + n * 16 + fr) * 64 + (((ks * 4 + fcb) ^ swz) * 8)];
            __builtin_amdgcn_s_setprio(1);
#pragma unroll
            for (int m = 0; m < 8; ++m)
#pragma unroll
                for (int n = 0; n < 4; ++n)
                    acc[m][n] = __builtin_amdgcn_mfma_f32_16x16x32_bf16(
                                    av[m], bv[n], acc[m][n], 0, 0, 0);
            __builtin_amdgcn_s_setprio(0);
        }
        asm volatile("s_waitcnt vmcnt(0)" ::: "memory");   // kt+1 staged
        asm volatile("s_barrier" ::: "memory");            // all reads of c done
    }

    // ---- epilogue: LDS bounce -> coalesced streams ----
    float* fsm = (float*)smem;               // 128 x 256 f32 = 128 KiB
    const int row_h = (l >> 4) * 4;
#pragma unroll 1
    for (int hh = 0; hh < 2; ++hh) {
        __syncthreads();
        if (wr == hh) {
#pragma unroll
            for (int m = 0; m < 8; ++m)
#pragma unroll
                for (int j = 0; j < 4; ++j) {
                    const int rl = m * 16 + row_h + j;
#pragma unroll
                    for (int n = 0; n < 4; ++n)
                        fsm[rl * 256 + wc * 64 + n * 16 + fr] = acc[m][n][j];
                }
        }
        __syncthreads();
#pragma unroll
        for (int it = 0; it < 16; ++it) {
            const int fid = it * 512 + tid;          // 0..8191 float4 ids
            const int rl = fid >> 6;
            const int cf = (fid & 63) * 4;
            float4 v = *(const float4*)&fsm[rl * 256 + cf];
            v.x += bias[bn + cf + 0];
            v.y += bias[bn + cf + 1];
            v.z += bias[bn + cf + 2];
            v.w += bias[bn + cf + 3];
            if (OUTB) {
                u16x4 o;
                o[0] = f2b(v.x); o[1] = f2b(v.y); o[2] = f2b(v.z); o[3] = f2b(v.w);
                *(u16x4*)&Cb[(size_t)(bm + hh * 128 + rl) * ldc + bn + cf] = o;
            } else {
                *(float4*)&Cf[(size_t)(bm + hh * 128 + rl) * ldc + bn + cf] = v;
            }
        }
    }
}

// ===========================================================================
// 128x128 m97-structure tile for conv GEMMs (dual (l,k) pair)
// ===========================================================================
template<int EPI>
__device__ __forceinline__ void gemm_tile(
    int bm, int bn,
    int K1, const u16* A1, int lda1, const u16* B1, int ldb1,
    int K2, const u16* A2, int lda2, const u16* B2, int ldb2,
    const float* bias,
    const float* bng, const float* bnb, const float* bnm, const float* bnv,
    u16* Cb, int ldc)
{
    __shared__ __align__(16) u16 As[128 * 32];
    __shared__ __align__(16) u16 Bs[128 * 32];

    const int tid  = threadIdx.x;
    const int lane = tid & 63;
    const int w    = tid >> 6;
    const int wr   = w >> 1, wc = w & 1;
    const int r_in = lane >> 2;
    const int c_in = (lane & 3) * 8;

    f32x4 acc[4][4];
#pragma unroll
    for (int m = 0; m < 4; ++m)
#pragma unroll
        for (int n = 0; n < 4; ++n) acc[m][n] = (f32x4){0.f, 0.f, 0.f, 0.f};

#pragma unroll 1
    for (int pair = 0; pair < 2; ++pair) {
        const int K = pair ? K2 : K1;
        if (K == 0) continue;
        const int lda = pair ? lda2 : lda1;
        const int ldb = pair ? ldb2 : ldb1;
        const u16* Ag = (pair ? A2 : A1) + (size_t)bm * lda;
        const u16* Bg = (pair ? B2 : B1) + (size_t)bn * ldb;

        for (int k0 = 0; k0 < K; k0 += 32) {
#pragma unroll
            for (int i = 0; i < 2; ++i) {
                gload_lds16(Ag + (size_t)(i * 64 + w * 16 + r_in) * lda + k0 + c_in,
                            &As[i * 2048 + w * 512]);
                gload_lds16(Bg + (size_t)(i * 64 + w * 16 + r_in) * ldb + k0 + c_in,
                            &Bs[i * 2048 + w * 512]);
            }
            __syncthreads();

            const int fr = lane & 15;
            const int fk = (lane >> 4) * 8;
            bf16x8 av[4], bv[4];
#pragma unroll
            for (int m = 0; m < 4; ++m)
                av[m] = *(const bf16x8*)&As[(wr * 64 + m * 16 + fr) * 32 + fk];
#pragma unroll
            for (int n = 0; n < 4; ++n)
                bv[n] = *(const bf16x8*)&Bs[(wc * 64 + n * 16 + fr) * 32 + fk];
#pragma unroll
            for (int m = 0; m < 4; ++m)
#pragma unroll
                for (int n = 0; n < 4; ++n)
                    acc[m][n] = __builtin_amdgcn_mfma_f32_16x16x32_bf16(
                                    av[m], bv[n], acc[m][n], 0, 0, 0);
            __syncthreads();
        }
    }

    const int col_l = lane & 15;
    const int row_h = (lane >> 4) * 4;
#pragma unroll
    for (int m = 0; m < 4; ++m) {
#pragma unroll
        for (int j = 0; j < 4; ++j) {
            const int row = bm + wr * 64 + m * 16 + row_h + j;
#pragma unroll
            for (int n = 0; n < 4; ++n) {
                const int col = bn + wc * 64 + n * 16 + col_l;
                float v = acc[m][n][j] + bias[col];
                if (EPI == 1) {
                    float e = v > 0.f ? v : expm1f(v);
                    float sc = bng[col] * rsqrtf(bnv[col] + EPSV);
                    v = (e - bnm[col]) * sc + bnb[col];
                }
                Cb[(size_t)row * ldc + col] = f2b(v);
            }
        }
    }
}

template<int EPI>
__launch_bounds__(256)
__global__ void conv_gemm(int Lin, const u16* X, const u16* W, const float* bias,
                          const float* bng, const float* bnb, const float* bnm, const float* bnv,
                          u16* Y)
{
    const int t = blockIdx.z;
    int l0 = 0, k0 = 0, l1 = 0, k1 = 0, cnt = 0;
    for (int l = 0; l < Lin; ++l) {
        int k = t - 2 * l;
        if (k >= 0 && k < 3) { if (!cnt) { l0 = l; k0 = k; } else { l1 = l; k1 = k; } ++cnt; }
    }
    const size_t BH = (size_t)BATCH * HD, HH = (size_t)HD * HD;
    gemm_tile<EPI>(blockIdx.y * 128, blockIdx.x * 128,
        HD, X + l0 * BH, HD, W + k0 * HH, HD,
        cnt > 1 ? HD : 0, X + l1 * BH, HD, W + k1 * HH, HD,
        bias, bng, bnb, bnm, bnv, Y + (size_t)t * BH, HD);
}

// ===========================================================================
// Whole GRU chain in ONE cooperative launch. 256 blocks x 256 thr (1/CU).
// Per step: phase A (blocks 0..127): inp = relu(h_{t-1}@wx^T+xb);
//           grid.sync; phase B (all 256): gh+gi in regs + cell; grid.sync.
// ===========================================================================
#define KTILE(Ag, lda_, Bg, ldb_, k0_, ACC2)                                      \
  {                                                                               \
    const int k0 = (k0_);                                                         \
    gload_lds16((Ag) + (size_t)(tid >> 2) * (lda_) + k0 + (tid & 3) * 8,          \
                &As[tid * 8]);                                                    \
    _Pragma("unroll")                                                             \
    for (int i_ = 0; i_ < 3; ++i_) {                                              \
      const int u_ = tid + i_ * 256;                                              \
      gload_lds16((Bg) + (size_t)((u_ >> 8) * HD + bn + ((u_ & 255) >> 2)) * (ldb_)\
                       + k0 + (u_ & 3) * 8,                                       \
                  &Bs[u_ * 8]);                                                   \
    }                                                                             \
    __syncthreads();                                                              \
    {                                                                             \
      bf16x8 av0 = *(const bf16x8*)&As[(wr * 32 + fr) * 32 + fk];                 \
      bf16x8 av1 = *(const bf16x8*)&As[(wr * 32 + 16 + fr) * 32 + fk];            \
      _Pragma("unroll")                                                           \
      for (int n_ = 0; n_ < 2; ++n_) {                                            \
        const int bo = (wc * 32 + n_ * 16 + fr) * 32 + fk;                        \
        bf16x8 bv = *(const bf16x8*)&Bs[bo];                                      \
        ar[0][n_] = __builtin_amdgcn_mfma_f32_16x16x32_bf16(av0, bv, ar[0][n_], 0, 0, 0); \
        ar[1][n_] = __builtin_amdgcn_mfma_f32_16x16x32_bf16(av1, bv, ar[1][n_], 0, 0, 0); \
        bv = *(const bf16x8*)&Bs[2048 + bo];                                      \
        az[0][n_] = __builtin_amdgcn_mfma_f32_16x16x32_bf16(av0, bv, az[0][n_], 0, 0, 0); \
        az[1][n_] = __builtin_amdgcn_mfma_f32_16x16x32_bf16(av1, bv, az[1][n_], 0, 0, 0); \
        bv = *(const bf16x8*)&Bs[4096 + bo];                                      \
        ACC2[0][n_] = __builtin_amdgcn_mfma_f32_16x16x32_bf16(av0, bv, ACC2[0][n_], 0, 0, 0); \
        ACC2[1][n_] = __builtin_amdgcn_mfma_f32_16x16x32_bf16(av1, bv, ACC2[1][n_], 0, 0, 0); \
      }                                                                           \
    }                                                                             \
    __syncthreads();                                                              \
  }

__launch_bounds__(256)
__global__ void gru_chain(
    const u16* __restrict__ wih,  const u16* __restrict__ whh,
    const u16* __restrict__ wx,   const float* __restrict__ xb,
    const u16* __restrict__ gdecb, const float* __restrict__ extra0,
    const float* __restrict__ b_hh,
    const float* __restrict__ zf, const u16* __restrict__ zb,
    u16* __restrict__ inpb, u16* __restrict__ hsb,
    float* __restrict__ h0f, float* __restrict__ h1f)
{
    cooperative_groups::grid_group gg = cooperative_groups::this_grid();

    __shared__ __align__(16) u16 As[64 * 32];
    __shared__ __align__(16) u16 Bs[3 * 64 * 32];

    const int bid = blockIdx.x;
    const int tid = threadIdx.x, l = tid & 63, w = tid >> 6;
    const int wr = w >> 1, wc = w & 1;
    const int fr = l & 15, fk = (l >> 4) * 8;
    const int rh = (l >> 4) * 4;
    const size_t BH = (size_t)BATCH * HD;
    const size_t B3H = (size_t)BATCH * 3 * HD;

    for (int t = 0; t < TSTEPS; ++t) {
        const u16* hbp = t ? hsb + (size_t)(t - 1) * BH : zb;

        // ---- phase A: inp = relu(h_{t-1} @ wx^T + xb)  (t>0, blocks 0..127) ----
        if (t > 0 && bid < 128) {
            const int bm = (bid >> 3) * 64;
            const int bn = (bid & 7) * 64;
            f32x4 acc[2][2];
#pragma unroll
            for (int m = 0; m < 2; ++m)
#pragma unroll
                for (int n = 0; n < 2; ++n) acc[m][n] = (f32x4){0.f, 0.f, 0.f, 0.f};
            const u16* Ag = hbp + (size_t)bm * HD;
            const u16* Bg = wx + (size_t)bn * HD;
            for (int kt = 0; kt < 32; ++kt) {
                const int k0 = kt * 32;
                gload_lds16(Ag + (size_t)(tid >> 2) * HD + k0 + (tid & 3) * 8, &As[tid * 8]);
                gload_lds16(Bg + (size_t)(tid >> 2) * HD + k0 + (tid & 3) * 8, &Bs[tid * 8]);
                __syncthreads();
                bf16x8 av0 = *(const bf16x8*)&As[(wr * 32 + fr) * 32 + fk];
                bf16x8 av1 = *(const bf16x8*)&As[(wr * 32 + 16 + fr) * 32 + fk];
#pragma unroll
                for (int n = 0; n < 2; ++n) {
                    bf16x8 bv = *(const bf16x8*)&Bs[(wc * 32 + n * 16 + fr) * 32 + fk];
                    acc[0][n] = __builtin_amdgcn_mfma_f32_16x16x32_bf16(av0, bv, acc[0][n], 0, 0, 0);
                    acc[1][n] = __builtin_amdgcn_mfma_f32_16x16x32_bf16(av1, bv, acc[1][n], 0, 0, 0);
                }
                __syncthreads();
            }
#pragma unroll
            for (int m = 0; m < 2; ++m)
#pragma unroll
                for (int n = 0; n < 2; ++n)
#pragma unroll
                    for (int j = 0; j < 4; ++j) {
                        const int R = bm + wr * 32 + m * 16 + rh + j;
                        const int C = bn + wc * 32 + n * 16 + fr;
                        inpb[(size_t)R * IND + C] = f2b(fmaxf(acc[m][n][j] + xb[C], 0.f));
                    }
        }
        gg.sync();

        // ---- phase B: gh (K=1024) + gi (K=512) + cell ----
        {
            const int bm = (bid >> 4) * 64;
            const int bn = (bid & 15) * 64;
            f32x4 ar[2][2], az[2][2], ain[2][2], ahn[2][2];
#pragma unroll
            for (int m = 0; m < 2; ++m)
#pragma unroll
                for (int n = 0; n < 2; ++n) {
                    ar[m][n] = (f32x4){0.f, 0.f, 0.f, 0.f};
                    az[m][n] = (f32x4){0.f, 0.f, 0.f, 0.f};
                    ain[m][n] = (f32x4){0.f, 0.f, 0.f, 0.f};
                    ahn[m][n] = (f32x4){0.f, 0.f, 0.f, 0.f};
                }
            const u16* Ah = hbp + (size_t)bm * HD;
            const u16* Ai = inpb + (size_t)bm * IND;
            for (int kt = 0; kt < 32; ++kt)
                KTILE(Ah, HD, whh, HD, kt * 32, ahn);
            if (t > 0)
                for (int kt = 0; kt < 16; ++kt)
                    KTILE(Ai, IND, wih, (IND + HD), kt * 32, ain);

            const u16* gdect = gdecb + (size_t)t * B3H;
            const float* e0 = (t == 0) ? extra0 : nullptr;
            const float* hp = (t == 0) ? zf : (((t - 1) & 1) ? h1f : h0f);
            float* hw = (t & 1) ? h1f : h0f;
            u16* hsbt = hsb + (size_t)t * BH;
#pragma unroll
            for (int m = 0; m < 2; ++m)
#pragma unroll
                for (int n = 0; n < 2; ++n)
#pragma unroll
                    for (int j = 0; j < 4; ++j) {
                        const int R = bm + wr * 32 + m * 16 + rh + j;
                        const int C = bn + wc * 32 + n * 16 + fr;
                        const size_t g3 = (size_t)R * (3 * HD);
                        float gr  = ar[m][n][j] + b2f(gdect[g3 + C])      + b_hh[C];
                        float gz  = az[m][n][j] + b2f(gdect[g3 + HD + C]) + b_hh[HD + C];
                        float gin = ain[m][n][j] + b2f(gdect[g3 + 2 * HD + C]);
                        float ghn = ahn[m][n][j] + b_hh[2 * HD + C];
                        if (e0) {
                            gr  += e0[C];
                            gz  += e0[HD + C];
                            gin += e0[2 * HD + C];
                        }
                        const float rg = 1.f / (1.f + expf(-gr));
                        const float zg = 1.f / (1.f + expf(-gz));
                        const float nn = tanhf(gin + rg * ghn);
                        const float h  = (1.f - zg) * nn + zg * hp[(size_t)R * HD + C];
                        hw[(size_t)R * HD + C] = h;
                        hsbt[(size_t)R * HD + C] = f2b(h);
                    }
        }
        gg.sync();
    }
}

// ---------------------------------------------------------------------------
__global__ void pack_w(const float* __restrict__ cw, u16* __restrict__ wp)
{   // (H,H,3) raw [o,i,k] -> bf16 (3,H,H) [k][o][i]
    __shared__ float lds[768];
    const int o = blockIdx.x, t = threadIdx.x;
    const float* src = cw + (size_t)o * (HD * 3);
    for (int i0 = 0; i0 < HD; i0 += 256) {
#pragma unroll
        for (int r = 0; r < 3; ++r) lds[t + 256 * r] = src[i0 * 3 + t + 256 * r];
        __syncthreads();
#pragma unroll
        for (int k = 0; k < 3; ++k)
            wp[(size_t)k * HD * HD + (size_t)o * HD + i0 + t] = f2b(lds[t * 3 + k]);
        __syncthreads();
    }
}

__global__ void f32_to_b16(const float* __restrict__ s, u16* __restrict__ d, int n)
{
    int i = (blockIdx.x * 256 + threadIdx.x) * 8;
    if (i >= n) return;
    float4 a = *(const float4*)(s + i);
    float4 b = *(const float4*)(s + i + 4);
    u16x8 o;
    o[0] = f2b(a.x); o[1] = f2b(a.y); o[2] = f2b(a.z); o[3] = f2b(a.w);
    o[4] = f2b(b.x); o[5] = f2b(b.y); o[6] = f2b(b.z); o[7] = f2b(b.w);
    *(u16x8*)(d + i) = o;
}

// extra0[j] = 8190 * sum_{k<IND} w_ih[j,k]  (fp32-exact t=0 inp contribution)
__global__ void ext0_k(const float* __restrict__ w_ih, float* __restrict__ e0)
{
    const int j = blockIdx.x, lane = threadIdx.x;   // 64 lanes
    float s = 0.f;
    for (int k = lane; k < IND; k += 64) s += w_ih[(size_t)j * (IND + HD) + k];
    for (int off = 32; off; off >>= 1) s += __shfl_down(s, off);
    if (lane == 0) e0[j] = 8190.f * s;
}

// ---------------------------------------------------------------------------
extern "C" void kernel_launch(void* const* d_in, const int* in_sizes, int n_in,
                              void* d_out, int out_size, void* d_ws, size_t ws_size,
                              hipStream_t stream)
{
    (void)in_sizes; (void)n_in; (void)out_size; (void)ws_size;

    const float* z    = (const float*)d_in[0];
    const float* cw1  = (const float*)d_in[2];
    const float* cb1  = (const float*)d_in[3];
    const float* cw2  = (const float*)d_in[4];
    const float* cb2  = (const float*)d_in[5];
    const float* cw3  = (const float*)d_in[6];
    const float* cb3  = (const float*)d_in[7];
    const float* bn1g = (const float*)d_in[8];
    const float* bn1b = (const float*)d_in[9];
    const float* bn1m = (const float*)d_in[10];
    const float* bn1v = (const float*)d_in[11];
    const float* bn2g = (const float*)d_in[12];
    const float* bn2b = (const float*)d_in[13];
    const float* bn2m = (const float*)d_in[14];
    const float* bn2v = (const float*)d_in[15];
    const float* w_ih = (const float*)d_in[16];
    const float* w_hh = (const float*)d_in[17];
    const float* b_ih = (const float*)d_in[18];
    const float* b_hh = (const float*)d_in[19];
    const float* h2xw = (const float*)d_in[20];
    const float* h2xb = (const float*)d_in[21];
    const float* d2ow = (const float*)d_in[22];
    const float* d2ob = (const float*)d_in[23];
    const float* outw = (const float*)d_in[24];
    const float* outb = (const float*)d_in[25];

    const size_t HH = (size_t)HD * HD, BH = (size_t)BATCH * HD;
    const size_t B3H = (size_t)BATCH * 3 * HD;

    u16* wsb = (u16*)d_ws;
    size_t off = 0;
    auto A16 = [&](size_t n) { u16* p = wsb + off; off += n; return p; };
    u16* wp1   = A16(3 * HH);
    u16* wp2   = A16(3 * HH);
    u16* wp3   = A16(3 * HH);
    u16* wihb  = A16((size_t)3 * HD * (IND + HD));
    u16* whhb  = A16(3 * HH);
    u16* h2xbw = A16((size_t)IND * HD);
    u16* outwb = A16((size_t)OUTD * HD);
    u16* d2owb = A16((size_t)OUTD * HD);
    u16* zb    = A16(BH);
    u16* decab = A16(3 * BH);
    u16* decbb = A16(7 * BH);
    u16* dec3b = A16(15 * BH);
    u16* hsb   = A16(15 * BH);
    u16* inpb  = A16((size_t)BATCH * IND);
    u16* gdecb = A16((size_t)TSTEPS * B3H);     // bf16 gdec (~94 MB)
    float* wsf = (float*)(wsb + ((off + 1) & ~(size_t)1));
    size_t foff = 0;
    auto A32 = [&](size_t n) { float* p = wsf + foff; foff += n; return p; };
    float* h0f   = A32(BH);
    float* h1f   = A32(BH);
    float* extra0= A32(3 * HD);

    pack_w<<<HD, 256, 0, stream>>>(cw1, wp1);
    pack_w<<<HD, 256, 0, stream>>>(cw2, wp2);
    pack_w<<<HD, 256, 0, stream>>>(cw3, wp3);
    auto cvt = [&](const float* s, u16* d, size_t n) {
        f32_to_b16<<<(unsigned)(n / 2048), 256, 0, stream>>>(s, d, (int)n);
    };
    cvt(z, zb, BH);
    cvt(w_ih, wihb, (size_t)3 * HD * (IND + HD));
    cvt(w_hh, whhb, 3 * HH);
    cvt(h2xw, h2xbw, (size_t)IND * HD);
    cvt(outw, outwb, (size_t)OUTD * HD);
    cvt(d2ow, d2owb, (size_t)OUTD * HD);
    ext0_k<<<3 * HD, 64, 0, stream>>>(w_ih, extra0);

    conv_gemm<1><<<dim3(8, 8, 3), 256, 0, stream>>>(1, zb, wp1, cb1,
        bn1g, bn1b, bn1m, bn1v, decab);
    conv_gemm<1><<<dim3(8, 8, 7), 256, 0, stream>>>(3, decab, wp2, cb2,
        bn2g, bn2b, bn2m, bn2v, decbb);
    conv_gemm<0><<<dim3(8, 8, 15), 256, 0, stream>>>(7, decbb, wp3, cb3,
        nullptr, nullptr, nullptr, nullptr, dec3b);

    // gdec[t] = dec_tbh @ w_ih[:,512:]^T + b_ih  for all t (parallel, bf16 out)
    gemm256<1><<<dim3((TSTEPS * BATCH / 256) * (3 * HD / 256)), 512, 0, stream>>>(
        3 * HD / 256, HD / 64,
        dec3b, wihb + IND, b_ih, nullptr, gdecb, HD, IND + HD, 3 * HD);

    // ---- GRU chain: ONE cooperative launch ----
    {
        void* ka[] = {
            (void*)&wihb, (void*)&whhb, (void*)&h2xbw, (void*)&h2xb,
            (void*)&gdecb, (void*)&extra0, (void*)&b_hh,
            (void*)&z, (void*)&zb, (void*)&inpb, (void*)&hsb,
            (void*)&h0f, (void*)&h1f
        };
        hipLaunchCooperativeKernel((const void*)gru_chain,
            dim3(256), dim3(256), ka, 0, stream);
    }

    // output projections
    float* out0 = (float*)d_out;
    float* out1 = out0 + (size_t)TSTEPS * BATCH * OUTD;
    const int nbn = OUTD / 256;                       // 32
    const int nwg = (TSTEPS * BATCH / 256) * nbn;     // 1920
    gemm256<0><<<dim3(nwg), 512, 0, stream>>>(nbn, HD / 64,
        hsb, outwb, outb, out0, nullptr, HD, HD, OUTD);
    gemm256<0><<<dim3(nwg), 512, 0, stream>>>(nbn, HD / 64,
        dec3b, d2owb, d2ob, out1, nullptr, HD, HD, OUTD);
}

// Round 9
// 1537.483 us; speedup vs baseline: 1.6499x; 1.6499x over previous
//
#include <hip/hip_runtime.h>
#include <math.h>

// HybridDecoder. B=1024 H=1024 IN=512 OUT=8192 T=15.
// R9: revert coop launch (R8: grid.sync = L2-flush, +870us). Chain = R7 2-launch
//     structure, but each chain launch carries "rider" blocks computing 128^2
//     projection tiles (out1 on gih launches, out0[t-1] on h2x launches) in the
//     chain's idle-machine shadow. Separate projection launches removed.
// conv_transpose identity: y[n,o,t] = sum_{2l+k=t} x[n,i,l] * W[o,i,k]

#define HD    1024
#define BATCH 1024
#define IND   512
#define OUTD  8192
#define TSTEPS 15
#define EPSV  1e-5f

typedef unsigned short u16;
typedef __attribute__((ext_vector_type(8))) short bf16x8;
typedef __attribute__((ext_vector_type(8))) unsigned short u16x8;
typedef __attribute__((ext_vector_type(4))) unsigned short u16x4;
typedef __attribute__((ext_vector_type(4))) float f32x4;

__device__ __forceinline__ u16 f2b(float f) {          // fp32 -> bf16 RNE
    union { float f; unsigned u; } x; x.f = f;
    unsigned r = x.u + 0x7fffu + ((x.u >> 16) & 1u);
    return (u16)(r >> 16);
}
__device__ __forceinline__ float b2f(u16 v) {
    union { unsigned u; float f; } x; x.u = ((unsigned)v) << 16; return x.f;
}

typedef __attribute__((address_space(1))) const void gas_t;
typedef __attribute__((address_space(3))) void las_t;
__device__ __forceinline__ void gload_lds16(const u16* g, u16* l) {
    __builtin_amdgcn_global_load_lds((gas_t*)g, (las_t*)l, 16, 0, 0);
}

// ===========================================================================
// m97-structure 128x128 tile (256 thr, 16 KiB LDS via caller pointers)
// ===========================================================================
template<int EPI, bool WF32, bool WB16>
__device__ __forceinline__ void gemm_tile128(
    u16* As, u16* Bs,                    // each 128*32 u16
    int bm, int bn,
    int K1, const u16* A1, int lda1, const u16* B1, int ldb1,
    int K2, const u16* A2, int lda2, const u16* B2, int ldb2,
    const float* bias,
    const float* bng, const float* bnb, const float* bnm, const float* bnv,
    float* Cf, u16* Cb, int ldc)
{
    const int tid  = threadIdx.x;
    const int lane = tid & 63;
    const int w    = tid >> 6;
    const int wr   = w >> 1, wc = w & 1;
    const int r_in = lane >> 2;
    const int c_in = (lane & 3) * 8;

    f32x4 acc[4][4];
#pragma unroll
    for (int m = 0; m < 4; ++m)
#pragma unroll
        for (int n = 0; n < 4; ++n) acc[m][n] = (f32x4){0.f, 0.f, 0.f, 0.f};

#pragma unroll 1
    for (int pair = 0; pair < 2; ++pair) {
        const int K = pair ? K2 : K1;
        if (K == 0) continue;
        const int lda = pair ? lda2 : lda1;
        const int ldb = pair ? ldb2 : ldb1;
        const u16* Ag = (pair ? A2 : A1) + (size_t)bm * lda;
        const u16* Bg = (pair ? B2 : B1) + (size_t)bn * ldb;

        for (int k0 = 0; k0 < K; k0 += 32) {
#pragma unroll
            for (int i = 0; i < 2; ++i) {
                gload_lds16(Ag + (size_t)(i * 64 + w * 16 + r_in) * lda + k0 + c_in,
                            &As[i * 2048 + w * 512]);
                gload_lds16(Bg + (size_t)(i * 64 + w * 16 + r_in) * ldb + k0 + c_in,
                            &Bs[i * 2048 + w * 512]);
            }
            __syncthreads();

            const int fr = lane & 15;
            const int fk = (lane >> 4) * 8;
            bf16x8 av[4], bv[4];
#pragma unroll
            for (int m = 0; m < 4; ++m)
                av[m] = *(const bf16x8*)&As[(wr * 64 + m * 16 + fr) * 32 + fk];
#pragma unroll
            for (int n = 0; n < 4; ++n)
                bv[n] = *(const bf16x8*)&Bs[(wc * 64 + n * 16 + fr) * 32 + fk];
#pragma unroll
            for (int m = 0; m < 4; ++m)
#pragma unroll
                for (int n = 0; n < 4; ++n)
                    acc[m][n] = __builtin_amdgcn_mfma_f32_16x16x32_bf16(
                                    av[m], bv[n], acc[m][n], 0, 0, 0);
            __syncthreads();
        }
    }

    const int col_l = lane & 15;
    const int row_h = (lane >> 4) * 4;
#pragma unroll
    for (int m = 0; m < 4; ++m) {
#pragma unroll
        for (int j = 0; j < 4; ++j) {
            const int row = bm + wr * 64 + m * 16 + row_h + j;
#pragma unroll
            for (int n = 0; n < 4; ++n) {
                const int col = bn + wc * 64 + n * 16 + col_l;
                float v = acc[m][n][j] + bias[col];
                if (EPI == 1) {
                    float e = v > 0.f ? v : expm1f(v);
                    float sc = bng[col] * rsqrtf(bnv[col] + EPSV);
                    v = (e - bnm[col]) * sc + bnb[col];
                }
                if (WF32) Cf[(size_t)row * ldc + col] = v;
                if (WB16) Cb[(size_t)row * ldc + col] = f2b(v);
            }
        }
    }
}

// projection rider: tile g (row-tile g>>6, col-tile g&63), K=1024, fp32 out
__device__ __forceinline__ void proj_rider(u16* sm, int g,
    const u16* A, const u16* B, const float* bias, float* C)
{
    gemm_tile128<0, true, false>(sm, sm + 4096,
        (g >> 6) * 128, (g & 63) * 128,
        HD, A, HD, B, HD, 0, nullptr, 0, nullptr, 0,
        bias, nullptr, nullptr, nullptr, nullptr, C, nullptr, OUTD);
}

// ===========================================================================
// conv stage (dual (l,k) pair), bf16 out
// ===========================================================================
template<int EPI>
__launch_bounds__(256)
__global__ void conv_gemm(int Lin, const u16* X, const u16* W, const float* bias,
                          const float* bng, const float* bnb, const float* bnm, const float* bnv,
                          u16* Y)
{
    __shared__ __align__(16) u16 sm[8192];
    const int t = blockIdx.z;
    int l0 = 0, k0 = 0, l1 = 0, k1 = 0, cnt = 0;
    for (int l = 0; l < Lin; ++l) {
        int k = t - 2 * l;
        if (k >= 0 && k < 3) { if (!cnt) { l0 = l; k0 = k; } else { l1 = l; k1 = k; } ++cnt; }
    }
    const size_t BH = (size_t)BATCH * HD, HH = (size_t)HD * HD;
    gemm_tile128<EPI, false, true>(sm, sm + 4096,
        blockIdx.y * 128, blockIdx.x * 128,
        HD, X + l0 * BH, HD, W + k0 * HH, HD,
        cnt > 1 ? HD : 0, X + l1 * BH, HD, W + k1 * HH, HD,
        bias, bng, bnb, bnm, bnv, nullptr, Y + (size_t)t * BH, HD);
}

// ===========================================================================
// 256x256 GEMM (gdec only): bf16 out. R8 version (supertile + XCD swizzle).
// ===========================================================================
__launch_bounds__(512, 2)
__global__ void gemm256(int nbn, int nk,
    const u16* __restrict__ A, const u16* __restrict__ B,
    const float* __restrict__ bias, u16* __restrict__ Cb,
    int lda, int ldb, int ldc)
{
    const int nwg = gridDim.x;
    const int q = nwg >> 3, r = nwg & 7;
    const int xcd = blockIdx.x & 7, idx = blockIdx.x >> 3;
    const int wg = (xcd < r ? xcd * (q + 1) : r * (q + 1) + (xcd - r) * q) + idx;
    int bm, bn;
    const int nbm = nwg / nbn;
    if ((nbn & 3) == 0 && (nbm & 1) == 0) {
        const int nsc = nbn >> 2;
        const int super = wg >> 3, inner = wg & 7;
        const int sr = super / nsc, sc = super - sr * nsc;
        bm = (sr * 2 + (inner >> 2)) * 256;
        bn = (sc * 4 + (inner & 3)) * 256;
    } else {
        bm = (wg / nbn) * 256;
        bn = (wg % nbn) * 256;
    }

    __shared__ __align__(16) u16 smem[2][2][256 * 64];
    u16 (*As)[256 * 64] = smem[0];
    u16 (*Bs)[256 * 64] = smem[1];

    const int tid = threadIdx.x;
    const int w = tid >> 6, l = tid & 63;
    const int wr = w >> 2, wc = w & 3;
    const int srow = l >> 3;
    const int scb  = (l & 7) ^ srow;
    const int fr = l & 15, fcb = l >> 4, swz = l & 7;

    const u16* Ag = A + (size_t)bm * lda;
    const u16* Bg = B + (size_t)bn * ldb;

    auto stage = [&](int b, int kt) {
        const int k0 = kt * 64 + scb * 8;
#pragma unroll
        for (int rr = 0; rr < 4; ++rr)
            gload_lds16(Ag + (size_t)(rr * 64 + w * 8 + srow) * lda + k0,
                        &As[b][(rr * 64 + w * 8) * 64]);
#pragma unroll
        for (int rr = 0; rr < 4; ++rr)
            gload_lds16(Bg + (size_t)(rr * 64 + w * 8 + srow) * ldb + k0,
                        &Bs[b][(rr * 64 + w * 8) * 64]);
    };

    f32x4 acc[8][4];
#pragma unroll
    for (int m = 0; m < 8; ++m)
#pragma unroll
        for (int n = 0; n < 4; ++n) acc[m][n] = (f32x4){0.f, 0.f, 0.f, 0.f};

    stage(0, 0);
    asm volatile("s_waitcnt vmcnt(0)" ::: "memory");
    asm volatile("s_barrier" ::: "memory");

    for (int kt = 0; kt < nk; ++kt) {
        const int c = kt & 1;
        if (kt + 1 < nk) stage(c ^ 1, kt + 1);
#pragma unroll
        for (int ks = 0; ks < 2; ++ks) {
            bf16x8 av[8], bv[4];
#pragma unroll
            for (int m = 0; m < 8; ++m)
                av[m] = *(const bf16x8*)&As[c][
                    (wr * 128 + m * 16 + fr) * 64 + (((ks * 4 + fcb) ^ swz) * 8)];
#pragma unroll
            for (int n = 0; n < 4; ++n)
                bv[n] = *(const bf16x8*)&Bs[c][
                    (wc * 64 + n * 16 + fr) * 64 + (((ks * 4 + fcb) ^ swz) * 8)];
            __builtin_amdgcn_s_setprio(1);
#pragma unroll
            for (int m = 0; m < 8; ++m)
#pragma unroll
                for (int n = 0; n < 4; ++n)
                    acc[m][n] = __builtin_amdgcn_mfma_f32_16x16x32_bf16(
                                    av[m], bv[n], acc[m][n], 0, 0, 0);
            __builtin_amdgcn_s_setprio(0);
        }
        asm volatile("s_waitcnt vmcnt(0)" ::: "memory");
        asm volatile("s_barrier" ::: "memory");
    }

    float* fsm = (float*)smem;
    const int row_h = (l >> 4) * 4;
#pragma unroll 1
    for (int hh = 0; hh < 2; ++hh) {
        __syncthreads();
        if (wr == hh) {
#pragma unroll
            for (int m = 0; m < 8; ++m)
#pragma unroll
                for (int j = 0; j < 4; ++j) {
                    const int rl = m * 16 + row_h + j;
#pragma unroll
                    for (int n = 0; n < 4; ++n)
                        fsm[rl * 256 + wc * 64 + n * 16 + fr] = acc[m][n][j];
                }
        }
        __syncthreads();
#pragma unroll
        for (int it = 0; it < 16; ++it) {
            const int fid = it * 512 + tid;
            const int rl = fid >> 6;
            const int cf = (fid & 63) * 4;
            float4 v = *(const float4*)&fsm[rl * 256 + cf];
            v.x += bias[bn + cf + 0];
            v.y += bias[bn + cf + 1];
            v.z += bias[bn + cf + 2];
            v.w += bias[bn + cf + 3];
            u16x4 o;
            o[0] = f2b(v.x); o[1] = f2b(v.y); o[2] = f2b(v.z); o[3] = f2b(v.w);
            *(u16x4*)&Cb[(size_t)(bm + hh * 128 + rl) * ldc + bn + cf] = o;
        }
    }
}

// ===========================================================================
// GRU step kernels (R7 structure) + rider blocks
// ===========================================================================
#define KTILE(Ag, lda_, Bg, ldb_, k0_, ACC2)                                      \
  {                                                                               \
    const int k0 = (k0_);                                                         \
    gload_lds16((Ag) + (size_t)(tid >> 2) * (lda_) + k0 + (tid & 3) * 8,          \
                &As[tid * 8]);                                                    \
    _Pragma("unroll")                                                             \
    for (int i_ = 0; i_ < 3; ++i_) {                                              \
      const int u_ = tid + i_ * 256;                                              \
      gload_lds16((Bg) + (size_t)((u_ >> 8) * HD + bn + ((u_ & 255) >> 2)) * (ldb_)\
                       + k0 + (u_ & 3) * 8,                                       \
                  &Bs[u_ * 8]);                                                   \
    }                                                                             \
    __syncthreads();                                                              \
    {                                                                             \
      bf16x8 av0 = *(const bf16x8*)&As[(wr * 32 + fr) * 32 + fk];                 \
      bf16x8 av1 = *(const bf16x8*)&As[(wr * 32 + 16 + fr) * 32 + fk];            \
      _Pragma("unroll")                                                           \
      for (int n_ = 0; n_ < 2; ++n_) {                                            \
        const int bo = (wc * 32 + n_ * 16 + fr) * 32 + fk;                        \
        bf16x8 bv = *(const bf16x8*)&Bs[bo];                                      \
        ar[0][n_] = __builtin_amdgcn_mfma_f32_16x16x32_bf16(av0, bv, ar[0][n_], 0, 0, 0); \
        ar[1][n_] = __builtin_amdgcn_mfma_f32_16x16x32_bf16(av1, bv, ar[1][n_], 0, 0, 0); \
        bv = *(const bf16x8*)&Bs[2048 + bo];                                      \
        az[0][n_] = __builtin_amdgcn_mfma_f32_16x16x32_bf16(av0, bv, az[0][n_], 0, 0, 0); \
        az[1][n_] = __builtin_amdgcn_mfma_f32_16x16x32_bf16(av1, bv, az[1][n_], 0, 0, 0); \
        bv = *(const bf16x8*)&Bs[4096 + bo];                                      \
        ACC2[0][n_] = __builtin_amdgcn_mfma_f32_16x16x32_bf16(av0, bv, ACC2[0][n_], 0, 0, 0); \
        ACC2[1][n_] = __builtin_amdgcn_mfma_f32_16x16x32_bf16(av1, bv, ACC2[1][n_], 0, 0, 0); \
      }                                                                           \
    }                                                                             \
    __syncthreads();                                                              \
  }

// gih_cell: bid<256 = chain (gh+gi+cell); bid>=256 = rider on out1 tile t*512+rid
__launch_bounds__(256)
__global__ void gih_cell(int t,
    const u16* __restrict__ inpb,  const u16* __restrict__ wih,
    const u16* __restrict__ hbp,   const u16* __restrict__ whh,
    const u16* __restrict__ gdect, const float* __restrict__ extra0,
    const float* __restrict__ b_hh, const float* __restrict__ hp,
    float* __restrict__ hf, u16* __restrict__ hsbt,
    const u16* __restrict__ dec3b, const u16* __restrict__ d2owb,
    const float* __restrict__ d2ob, float* __restrict__ out1)
{
    __shared__ __align__(16) u16 sm[8192];
    const int bid = blockIdx.x;
    const int tid = threadIdx.x, l = tid & 63, w = tid >> 6;
    const int wr = w >> 1, wc = w & 1;
    const int fr = l & 15, fk = (l >> 4) * 8;

    if (bid >= 256) {   // rider: out1 = dec3b @ d2ow^T + d2ob
        proj_rider(sm, t * 512 + (bid - 256), dec3b, d2owb, d2ob, out1);
        return;
    }

    u16* As = sm;            // 64*32
    u16* Bs = sm + 2048;     // 3*64*32
    const int bm = (bid >> 4) * 64;
    const int bn = (bid & 15) * 64;

    f32x4 ar[2][2], az[2][2], ain[2][2], ahn[2][2];
#pragma unroll
    for (int m = 0; m < 2; ++m)
#pragma unroll
        for (int n = 0; n < 2; ++n) {
            ar[m][n] = (f32x4){0.f, 0.f, 0.f, 0.f};
            az[m][n] = (f32x4){0.f, 0.f, 0.f, 0.f};
            ain[m][n] = (f32x4){0.f, 0.f, 0.f, 0.f};
            ahn[m][n] = (f32x4){0.f, 0.f, 0.f, 0.f};
        }

    const u16* Ah = hbp + (size_t)bm * HD;
    const u16* Ai = inpb + (size_t)bm * IND;
    for (int kt = 0; kt < 32; ++kt)
        KTILE(Ah, HD, whh, HD, kt * 32, ahn);
    if (t > 0)
        for (int kt = 0; kt < 16; ++kt)
            KTILE(Ai, IND, wih, (IND + HD), kt * 32, ain);

    const int rh = (l >> 4) * 4;
#pragma unroll
    for (int m = 0; m < 2; ++m)
#pragma unroll
        for (int n = 0; n < 2; ++n)
#pragma unroll
            for (int j = 0; j < 4; ++j) {
                const int R = bm + wr * 32 + m * 16 + rh + j;
                const int C = bn + wc * 32 + n * 16 + fr;
                const size_t g3 = (size_t)R * (3 * HD);
                float gr  = ar[m][n][j] + b2f(gdect[g3 + C])      + b_hh[C];
                float gz  = az[m][n][j] + b2f(gdect[g3 + HD + C]) + b_hh[HD + C];
                float gin = ain[m][n][j] + b2f(gdect[g3 + 2 * HD + C]);
                float ghn = ahn[m][n][j] + b_hh[2 * HD + C];
                if (extra0) {
                    gr  += extra0[C];
                    gz  += extra0[HD + C];
                    gin += extra0[2 * HD + C];
                }
                const float rg = 1.f / (1.f + expf(-gr));
                const float zg = 1.f / (1.f + expf(-gz));
                const float nn = tanhf(gin + rg * ghn);
                const float h  = (1.f - zg) * nn + zg * hp[(size_t)R * HD + C];
                hf[(size_t)R * HD + C] = h;
                hsbt[(size_t)R * HD + C] = f2b(h);
            }
}

// h2x_k: bid<128 = chain (inp = relu(h@wx^T+xb)); bid>=128 = rider on out0
// tile (t-1)*512 + rid  (h_{t-1} rows of out0; hsb is t-major so A base = hsb)
__launch_bounds__(256)
__global__ void h2x_k(int t,
    const u16* __restrict__ hbp, const u16* __restrict__ wx,
    const float* __restrict__ xb, u16* __restrict__ inp,
    const u16* __restrict__ hsb, const u16* __restrict__ outwb,
    const float* __restrict__ outb, float* __restrict__ out0)
{
    __shared__ __align__(16) u16 sm[8192];
    const int bid = blockIdx.x;
    const int tid = threadIdx.x, l = tid & 63, w = tid >> 6;
    const int wr = w >> 1, wc = w & 1;
    const int fr = l & 15, fk = (l >> 4) * 8;

    if (bid >= 128) {   // rider: out0 tiles for step t-1
        proj_rider(sm, (t - 1) * 512 + (bid - 128), hsb, outwb, outb, out0);
        return;
    }

    u16* As = sm;
    u16* Bs = sm + 2048;
    const int bm = (bid >> 3) * 64;
    const int bn = (bid & 7) * 64;

    f32x4 acc[2][2];
#pragma unroll
    for (int m = 0; m < 2; ++m)
#pragma unroll
        for (int n = 0; n < 2; ++n) acc[m][n] = (f32x4){0.f, 0.f, 0.f, 0.f};
    const u16* Ag = hbp + (size_t)bm * HD;
    const u16* Bg = wx + (size_t)bn * HD;
    for (int kt = 0; kt < 32; ++kt) {
        const int k0 = kt * 32;
        gload_lds16(Ag + (size_t)(tid >> 2) * HD + k0 + (tid & 3) * 8, &As[tid * 8]);
        gload_lds16(Bg + (size_t)(tid >> 2) * HD + k0 + (tid & 3) * 8, &Bs[tid * 8]);
        __syncthreads();
        bf16x8 av0 = *(const bf16x8*)&As[(wr * 32 + fr) * 32 + fk];
        bf16x8 av1 = *(const bf16x8*)&As[(wr * 32 + 16 + fr) * 32 + fk];
#pragma unroll
        for (int n = 0; n < 2; ++n) {
            bf16x8 bv = *(const bf16x8*)&Bs[(wc * 32 + n * 16 + fr) * 32 + fk];
            acc[0][n] = __builtin_amdgcn_mfma_f32_16x16x32_bf16(av0, bv, acc[0][n], 0, 0, 0);
            acc[1][n] = __builtin_amdgcn_mfma_f32_16x16x32_bf16(av1, bv, acc[1][n], 0, 0, 0);
        }
        __syncthreads();
    }
    const int rh = (l >> 4) * 4;
#pragma unroll
    for (int m = 0; m < 2; ++m)
#pragma unroll
        for (int n = 0; n < 2; ++n)
#pragma unroll
            for (int j = 0; j < 4; ++j) {
                const int R = bm + wr * 32 + m * 16 + rh + j;
                const int C = bn + wc * 32 + n * 16 + fr;
                inp[(size_t)R * IND + C] = f2b(fmaxf(acc[m][n][j] + xb[C], 0.f));
            }
}

// tail: out0 tiles for step 14 (512 blocks)
__launch_bounds__(256)
__global__ void proj_k(int g0, const u16* __restrict__ A, const u16* __restrict__ B,
                       const float* __restrict__ bias, float* __restrict__ C)
{
    __shared__ __align__(16) u16 sm[8192];
    proj_rider(sm, g0 + blockIdx.x, A, B, bias, C);
}

// ---------------------------------------------------------------------------
__global__ void pack_w(const float* __restrict__ cw, u16* __restrict__ wp)
{   // (H,H,3) raw [o,i,k] -> bf16 (3,H,H) [k][o][i]
    __shared__ float lds[768];
    const int o = blockIdx.x, t = threadIdx.x;
    const float* src = cw + (size_t)o * (HD * 3);
    for (int i0 = 0; i0 < HD; i0 += 256) {
#pragma unroll
        for (int r = 0; r < 3; ++r) lds[t + 256 * r] = src[i0 * 3 + t + 256 * r];
        __syncthreads();
#pragma unroll
        for (int k = 0; k < 3; ++k)
            wp[(size_t)k * HD * HD + (size_t)o * HD + i0 + t] = f2b(lds[t * 3 + k]);
        __syncthreads();
    }
}

__global__ void f32_to_b16(const float* __restrict__ s, u16* __restrict__ d, int n)
{
    int i = (blockIdx.x * 256 + threadIdx.x) * 8;
    if (i >= n) return;
    float4 a = *(const float4*)(s + i);
    float4 b = *(const float4*)(s + i + 4);
    u16x8 o;
    o[0] = f2b(a.x); o[1] = f2b(a.y); o[2] = f2b(a.z); o[3] = f2b(a.w);
    o[4] = f2b(b.x); o[5] = f2b(b.y); o[6] = f2b(b.z); o[7] = f2b(b.w);
    *(u16x8*)(d + i) = o;
}

// extra0[j] = 8190 * sum_{k<IND} w_ih[j,k]  (fp32-exact t=0 inp contribution)
__global__ void ext0_k(const float* __restrict__ w_ih, float* __restrict__ e0)
{
    const int j = blockIdx.x, lane = threadIdx.x;   // 64 lanes
    float s = 0.f;
    for (int k = lane; k < IND; k += 64) s += w_ih[(size_t)j * (IND + HD) + k];
    for (int off = 32; off; off >>= 1) s += __shfl_down(s, off);
    if (lane == 0) e0[j] = 8190.f * s;
}

// ---------------------------------------------------------------------------
extern "C" void kernel_launch(void* const* d_in, const int* in_sizes, int n_in,
                              void* d_out, int out_size, void* d_ws, size_t ws_size,
                              hipStream_t stream)
{
    (void)in_sizes; (void)n_in; (void)out_size; (void)ws_size;

    const float* z    = (const float*)d_in[0];
    const float* cw1  = (const float*)d_in[2];
    const float* cb1  = (const float*)d_in[3];
    const float* cw2  = (const float*)d_in[4];
    const float* cb2  = (const float*)d_in[5];
    const float* cw3  = (const float*)d_in[6];
    const float* cb3  = (const float*)d_in[7];
    const float* bn1g = (const float*)d_in[8];
    const float* bn1b = (const float*)d_in[9];
    const float* bn1m = (const float*)d_in[10];
    const float* bn1v = (const float*)d_in[11];
    const float* bn2g = (const float*)d_in[12];
    const float* bn2b = (const float*)d_in[13];
    const float* bn2m = (const float*)d_in[14];
    const float* bn2v = (const float*)d_in[15];
    const float* w_ih = (const float*)d_in[16];
    const float* w_hh = (const float*)d_in[17];
    const float* b_ih = (const float*)d_in[18];
    const float* b_hh = (const float*)d_in[19];
    const float* h2xw = (const float*)d_in[20];
    const float* h2xb = (const float*)d_in[21];
    const float* d2ow = (const float*)d_in[22];
    const float* d2ob = (const float*)d_in[23];
    const float* outw = (const float*)d_in[24];
    const float* outb = (const float*)d_in[25];

    const size_t HH = (size_t)HD * HD, BH = (size_t)BATCH * HD;
    const size_t B3H = (size_t)BATCH * 3 * HD;

    u16* wsb = (u16*)d_ws;
    size_t off = 0;
    auto A16 = [&](size_t n) { u16* p = wsb + off; off += n; return p; };
    u16* wp1   = A16(3 * HH);
    u16* wp2   = A16(3 * HH);
    u16* wp3   = A16(3 * HH);
    u16* wihb  = A16((size_t)3 * HD * (IND + HD));
    u16* whhb  = A16(3 * HH);
    u16* h2xbw = A16((size_t)IND * HD);
    u16* outwb = A16((size_t)OUTD * HD);
    u16* d2owb = A16((size_t)OUTD * HD);
    u16* zb    = A16(BH);
    u16* decab = A16(3 * BH);
    u16* decbb = A16(7 * BH);
    u16* dec3b = A16(15 * BH);
    u16* hsb   = A16(15 * BH);
    u16* inpb  = A16((size_t)BATCH * IND);
    u16* gdecb = A16((size_t)TSTEPS * B3H);     // bf16 gdec (~94 MB)
    float* wsf = (float*)(wsb + ((off + 1) & ~(size_t)1));
    size_t foff = 0;
    auto A32 = [&](size_t n) { float* p = wsf + foff; foff += n; return p; };
    float* h0f   = A32(BH);
    float* h1f   = A32(BH);
    float* extra0= A32(3 * HD);

    pack_w<<<HD, 256, 0, stream>>>(cw1, wp1);
    pack_w<<<HD, 256, 0, stream>>>(cw2, wp2);
    pack_w<<<HD, 256, 0, stream>>>(cw3, wp3);
    auto cvt = [&](const float* s, u16* d, size_t n) {
        f32_to_b16<<<(unsigned)(n / 2048), 256, 0, stream>>>(s, d, (int)n);
    };
    cvt(z, zb, BH);
    cvt(w_ih, wihb, (size_t)3 * HD * (IND + HD));
    cvt(w_hh, whhb, 3 * HH);
    cvt(h2xw, h2xbw, (size_t)IND * HD);
    cvt(outw, outwb, (size_t)OUTD * HD);
    cvt(d2ow, d2owb, (size_t)OUTD * HD);
    ext0_k<<<3 * HD, 64, 0, stream>>>(w_ih, extra0);

    conv_gemm<1><<<dim3(8, 8, 3), 256, 0, stream>>>(1, zb, wp1, cb1,
        bn1g, bn1b, bn1m, bn1v, decab);
    conv_gemm<1><<<dim3(8, 8, 7), 256, 0, stream>>>(3, decab, wp2, cb2,
        bn2g, bn2b, bn2m, bn2v, decbb);
    conv_gemm<0><<<dim3(8, 8, 15), 256, 0, stream>>>(7, decbb, wp3, cb3,
        nullptr, nullptr, nullptr, nullptr, dec3b);

    // gdec[t] = dec_tbh @ w_ih[:,512:]^T + b_ih  for all t (parallel, bf16 out)
    gemm256<<<dim3((TSTEPS * BATCH / 256) * (3 * HD / 256)), 512, 0, stream>>>(
        3 * HD / 256, HD / 64,
        dec3b, wihb + IND, b_ih, gdecb, HD, IND + HD, 3 * HD);

    // ---- GRU chain with projection riders ----
    float* out0 = (float*)d_out;
    float* out1 = out0 + (size_t)TSTEPS * BATCH * OUTD;
    for (int t = 0; t < TSTEPS; ++t) {
        const u16* hbp   = t ? hsb + (size_t)(t - 1) * BH : zb;
        const float* hpf = (t == 0) ? z : (((t - 1) & 1) ? h1f : h0f);
        float* hwf = (t & 1) ? h1f : h0f;
        if (t > 0)   // 128 chain blocks + 512 riders (out0 rows of step t-1)
            h2x_k<<<640, 256, 0, stream>>>(t, hbp, h2xbw, h2xb, inpb,
                hsb, outwb, outb, out0);
        // 256 chain blocks + 512 riders (out1 tiles t*512..)
        gih_cell<<<768, 256, 0, stream>>>(t,
            inpb, wihb, hbp, whhb, gdecb + (size_t)t * B3H,
            t ? nullptr : extra0, b_hh, hpf, hwf, hsb + (size_t)t * BH,
            dec3b, d2owb, d2ob, out1);
    }
    // tail: out0 rows of step 14
    proj_k<<<512, 256, 0, stream>>>(14 * 512, hsb, outwb, outb, out0);
}